// Round 4
// baseline (766.659 us; speedup 1.0000x reference)
//
#include <hip/hip_runtime.h>
#include <hip/hip_bf16.h>
#include <math.h>

#define M_ROWS 100000
#define NG16 6250             // 100000 / 16 groups of 16 rows
#define ROWS_PER_XCD 12500    // legacy path
#define NTILES 49             // legacy path
#define NCHUNK 49152          // weight chunks (16B) total = 768 KB

typedef __attribute__((ext_vector_type(8)))  short  short8;
typedef __attribute__((ext_vector_type(4)))  float  float4v;
typedef __attribute__((ext_vector_type(16))) float  float16v;

__device__ __forceinline__ unsigned short bf16_rne(float f) {
    unsigned u = __builtin_bit_cast(unsigned, f);
    u += 0x7FFFu + ((u >> 16) & 1u);
    return (unsigned short)(u >> 16);
}

__device__ __forceinline__ float sigmoid_fast(float x) {
    return 1.0f / (1.0f + __expf(-x));
}
__device__ __forceinline__ float tanh_fast(float x) {
    return 1.0f - 2.0f / (__expf(2.0f * x) + 1.0f);   // correct limits at +/-inf
}

__device__ __forceinline__ unsigned pack2_rn(float lo, float hi) {
    __hip_bfloat162 t = __float22bfloat162_rn(float2{lo, hi});
    unsigned u;
    __builtin_memcpy(&u, &t, 4);
    return u;
}

__device__ __forceinline__ short8 pack_bf16x8(float4 a, float4 b) {
    union { short8 s; unsigned u[4]; } r;
    r.u[0] = pack2_rn(a.x, a.y);
    r.u[1] = pack2_rn(a.z, a.w);
    r.u[2] = pack2_rn(b.x, b.y);
    r.u[3] = pack2_rn(b.z, b.w);
    return r.s;
}

// ---------------------------------------------------------------------------
// prep (fused):
//  blocks [0, pack_blocks): LDS-staged transpose pack. Block b owns rows
//    [b*32, b*32+32) = groups 2b, 2b+1. Phase 1: fully-coalesced float4 reads
//    of X,H rows (consecutive lanes adjacent), convert bf16, ds_write into
//    slds[mat][row][col] (pad 264 for 16B-aligned rows). Phase 2: read the
//    MFMA A-fragment chunks from LDS and store LINEAR+coalesced to apack:
//      chunk index = gq*1024 + kc*128 + mat*64 + lane  (16 B units)
//      lane l holds 8 bf16: row = gq*16+(l&15), k = kc*32+(l>>4)*8+j.
//  next 192 blocks: weight swizzle f32 -> bf16 B-fragment chunks.
//    w16=1 (16-col slices): chunk = ((g16*8+kc)*6+s)*64+lane,
//      col = g16*16+(l&15), k = kc*32+(l>>4)*8+j, row_w = (s%3)*256+col.
//    w16=0: legacy 32-col layout.
//  next 391 blocks: row mask. last block: max-acc init + done counter.
// ---------------------------------------------------------------------------
__global__ void prep_kernel(const float* __restrict__ X,
                            const float* __restrict__ H,
                            const float* __restrict__ wih,
                            const float* __restrict__ whh,
                            const int* __restrict__ divided,
                            unsigned short* __restrict__ wswz,
                            unsigned short* __restrict__ apack,
                            unsigned int* __restrict__ maxacc,
                            int* __restrict__ maskbuf,
                            unsigned int* __restrict__ donecnt,
                            int pack_blocks, int w16)
{
    __shared__ unsigned short slds[2][32][264];   // 33.8 KB, rows 16B-aligned

    const int b   = blockIdx.x;
    const int tid = threadIdx.x;

    if (b < pack_blocks) {
        const int r0 = b * 32;
        #pragma unroll
        for (int it = 0; it < 16; ++it) {
            const int mat = it >> 3;
            const int idx = (it & 7) * 256 + tid;     // 0..2047
            const int row = idx >> 6;                 // 0..31
            const int c4  = idx & 63;                 // float4 col
            const float* sp = (mat ? H : X) + (size_t)(r0 + row) * 256 + c4 * 4;
            float4 v = *reinterpret_cast<const float4*>(sp);
            uint2 w;
            w.x = pack2_rn(v.x, v.y);
            w.y = pack2_rn(v.z, v.w);
            *reinterpret_cast<uint2*>(&slds[mat][row][c4 * 4]) = w;
        }
        __syncthreads();
        #pragma unroll
        for (int it = 0; it < 8; ++it) {
            const int o    = it * 256 + tid;          // 0..2047
            const int gl   = o >> 10;
            const int kc   = (o >> 7) & 7;
            const int mat  = (o >> 6) & 1;
            const int lane = o & 63;
            const int rl   = gl * 16 + (lane & 15);
            const int col  = kc * 32 + (lane >> 4) * 8;
            short8 v = *reinterpret_cast<const short8*>(&slds[mat][rl][col]);
            reinterpret_cast<short8*>(apack)[(size_t)b * 2048 + o] = v;
        }
        return;
    }

    int bb = b - pack_blocks;
    if (bb < 192) {
        int idx  = bb * 256 + tid;        // < 49152
        int lane = idx & 63;
        int t    = idx >> 6;              // 0..767
        int s    = t % 6;
        int t2   = t / 6;                 // 0..127
        int row, col;
        if (w16) {
            int kc  = t2 & 7;
            int g16 = t2 >> 3;            // 0..15
            row = (s % 3) * 256 + g16 * 16 + (lane & 15);
            col = kc * 32 + (lane >> 4) * 8;
        } else {
            int kc = t2 & 15;
            int g  = t2 >> 4;             // 0..7
            row = (s % 3) * 256 + g * 32 + (lane & 31);
            col = kc * 16 + (lane >> 5) * 8;
        }
        const float* src = (s < 3 ? wih : whh) + (size_t)row * 256 + col;
        float4 a = reinterpret_cast<const float4*>(src)[0];
        float4 c = reinterpret_cast<const float4*>(src)[1];
        uint4 p;
        p.x = (unsigned)bf16_rne(a.x) | ((unsigned)bf16_rne(a.y) << 16);
        p.y = (unsigned)bf16_rne(a.z) | ((unsigned)bf16_rne(a.w) << 16);
        p.z = (unsigned)bf16_rne(c.x) | ((unsigned)bf16_rne(c.y) << 16);
        p.w = (unsigned)bf16_rne(c.z) | ((unsigned)bf16_rne(c.w) << 16);
        reinterpret_cast<uint4*>(wswz)[idx] = p;
    } else if (bb < 192 + 391) {
        int m = (bb - 192) * 256 + tid;
        if (m < M_ROWS)
            maskbuf[m] = (divided[3 * m] > 0) | (divided[3 * m + 1] > 0) | (divided[3 * m + 2] > 0);
    } else {
        maxacc[tid] = 0u;                 // below ordered-map(-inf)
        if (tid == 0) *donecnt = 0u;
    }
}

// ---------------------------------------------------------------------------
// main (16x16x32): 256-thread blocks (4 waves), 48 KB weight slice in LDS ->
// 3 blocks/CU co-resident (12 waves/CU, 1.5x the 32x32 version's 8).
// grid = 768 = (xcd: b&7) x (g16: slot&15) x (sub: slot>>4, 0..5) — exactly
// co-resident, persistent. Wave owns one 16-row group per round; rounds step
// by 24 (6 subs x 4 waves). Cross-group A-ring: refills at kc>=4 fetch the
// next group's kc 0..3, so group boundaries expose no cold latency.
// Epilogue H/mask prefetched before the MFMA loop (hides under MFMAs).
// C/D map (m89-verified family): col = lane&15, row = (lane>>4)*4 + reg.
// ---------------------------------------------------------------------------
__global__ __launch_bounds__(256, 3) void gru_main16(
    const unsigned short* __restrict__ Apack,
    const float* __restrict__ H,
    const unsigned short* __restrict__ Wswz,
    const float* __restrict__ bih,
    const float* __restrict__ bhh,
    const int* __restrict__ maskbuf,
    const float* __restrict__ interval,
    const float* __restrict__ time_w,
    const float* __restrict__ time_b,
    float* __restrict__ hnew,
    unsigned int* __restrict__ maxacc,
    unsigned int* __restrict__ donecnt,
    float* __restrict__ out)
{
    __shared__ unsigned short Wlds[24576];        // 48 KB (one g16-slice)
    __shared__ int islast;

    const int tid  = threadIdx.x;
    const int lane = tid & 63;
    const int wave = tid >> 6;                    // 0..3
    const int l16  = lane & 15;
    const int q    = lane >> 4;                   // 0..3

    const int b    = blockIdx.x;
    const int xcd  = b & 7;
    const int slot = b >> 3;                      // 0..95
    const int g16  = slot & 15;
    const int sub  = slot >> 4;                   // 0..5

    const int gbeg = xcd * 781 + (xcd < 2 ? xcd : 2);
    const int gend = gbeg + 781 + (xcd < 2 ? 1 : 0);

    // ---- one-time weight stage: contiguous 48 KB slice -> LDS ----
    {
        const uint4* ws = reinterpret_cast<const uint4*>(Wswz) + (size_t)g16 * 3072;
        uint4* wd = reinterpret_cast<uint4*>(Wlds);
        #pragma unroll
        for (int i = 0; i < 12; ++i) wd[i * 256 + tid] = ws[i * 256 + tid];
    }
    __syncthreads();

    const short8* wbase = reinterpret_cast<const short8*>(Wlds);
    const short8* A8b   = reinterpret_cast<const short8*>(Apack);
    const int jj = g16 * 16 + l16;
    const float bir = bih[jj], biz = bih[256 + jj], bin_ = bih[512 + jj];
    const float bhr = bhh[jj], bhz = bhh[256 + jj], bhn  = bhh[512 + jj];

    float colmax = -__builtin_inff();

    int g0 = gbeg + sub * 4 + wave;               // wave-uniform
    if (g0 < gend) {
        // prologue: fill 4-deep ring with first group's kc 0..3
        const short8* A8 = A8b + (size_t)g0 * 1024 + lane;
        short8 bx[4], bh[4];
        #pragma unroll
        for (int p = 0; p < 4; ++p) { bx[p] = A8[p * 128]; bh[p] = A8[p * 128 + 64]; }

        for (int g = g0; g < gend; g += 24) {
            A8 = A8b + (size_t)g * 1024 + lane;
            int gn = g + 24; if (gn >= gend) gn = g;           // clamp (last iter)
            const short8* An = A8b + (size_t)gn * 1024 + lane;

            // epilogue operand prefetch (independent; completes under MFMAs)
            float hp[4]; int mk[4];
            #pragma unroll
            for (int r = 0; r < 4; ++r) {
                const int m = g * 16 + q * 4 + r;
                hp[r] = H[(size_t)m * 256 + jj];
                mk[r] = maskbuf[m];
            }

            float4v acc[6];
            #pragma unroll
            for (int s = 0; s < 6; ++s)
                #pragma unroll
                for (int r = 0; r < 4; ++r) acc[s][r] = 0.0f;

            #pragma unroll
            for (int kc = 0; kc < 8; ++kc) {
                const int sl = kc & 3;
                const short8 ax = bx[sl], ah = bh[sl];
                if (kc < 4) { bx[sl] = A8[(kc + 4) * 128]; bh[sl] = A8[(kc + 4) * 128 + 64]; }
                else        { bx[sl] = An[(kc - 4) * 128]; bh[sl] = An[(kc - 4) * 128 + 64]; }
                const short8* wk = wbase + kc * 384 + lane;
                acc[0] = __builtin_amdgcn_mfma_f32_16x16x32_bf16(ax, wk[0],   acc[0], 0, 0, 0);
                acc[1] = __builtin_amdgcn_mfma_f32_16x16x32_bf16(ax, wk[64],  acc[1], 0, 0, 0);
                acc[2] = __builtin_amdgcn_mfma_f32_16x16x32_bf16(ax, wk[128], acc[2], 0, 0, 0);
                acc[3] = __builtin_amdgcn_mfma_f32_16x16x32_bf16(ah, wk[192], acc[3], 0, 0, 0);
                acc[4] = __builtin_amdgcn_mfma_f32_16x16x32_bf16(ah, wk[256], acc[4], 0, 0, 0);
                acc[5] = __builtin_amdgcn_mfma_f32_16x16x32_bf16(ah, wk[320], acc[5], 0, 0, 0);
            }

            // ---- fused GRU epilogue ----
            #pragma unroll
            for (int r = 0; r < 4; ++r) {
                const int m = g * 16 + q * 4 + r;
                float gir = acc[0][r] + bir;
                float giz = acc[1][r] + biz;
                float gin = acc[2][r] + bin_;
                float ghr = acc[3][r] + bhr;
                float ghz = acc[4][r] + bhz;
                float ghn = acc[5][r] + bhn;
                float rr = sigmoid_fast(gir + ghr);
                float z  = sigmoid_fast(giz + ghz);
                float n  = tanh_fast(gin + rr * ghn);
                float hv = (1.0f - z) * n + z * hp[r];
                __builtin_nontemporal_store(mk[r] ? hv : 0.0f, &hnew[(size_t)m * 256 + jj]);
                if (mk[r]) colmax = fmaxf(colmax, hv);
            }
        }
    }

    // lanes sharing a column: lane, lane^16, lane^32, lane^48
    colmax = fmaxf(colmax, __shfl_xor(colmax, 16));
    colmax = fmaxf(colmax, __shfl_xor(colmax, 32));
    if (lane < 16) {
        unsigned bb2 = __builtin_bit_cast(unsigned, colmax);
        unsigned u   = (bb2 & 0x80000000u) ? ~bb2 : (bb2 | 0x80000000u);
        atomicMax(&maxacc[jj], u);
    }

    // ---- fused finalize: last block to finish ----
    __syncthreads();
    if (tid == 0) {
        __threadfence();
        islast = (atomicAdd(donecnt, 1u) == 767u) ? 1 : 0;
    }
    __syncthreads();
    if (islast) {
        // all 767 other blocks' atomicMax results are fence-ordered before the
        // winning atomicAdd; volatile load is sufficient here.
        unsigned u   = ((volatile unsigned int*)maxacc)[tid];
        unsigned bb2 = (u & 0x80000000u) ? (u & 0x7FFFFFFFu) : ~u;
        float mx  = __builtin_bit_cast(float, bb2);
        float inv = 1.0f / logf(interval[0] + 2.718281828459045f);
        out[tid]  = mx + tanhf(inv * time_w[tid] + time_b[tid]);
    }
}

// ---------------------------------------------------------------------------
// legacy path (fallback when workspace is too small for the packed-A buffer)
// ---------------------------------------------------------------------------
__global__ __launch_bounds__(512, 2) void gru_main_legacy(
    const float* __restrict__ X,
    const float* __restrict__ H,
    const unsigned short* __restrict__ Wswz,
    const float* __restrict__ bih,
    const float* __restrict__ bhh,
    const int* __restrict__ maskbuf,
    float* __restrict__ hnew,
    unsigned int* __restrict__ maxacc)
{
    __shared__ unsigned short Wlds[NCHUNK];

    const int tid  = threadIdx.x;
    const int lane = tid & 63;
    const int wave = tid >> 6;
    const int l32  = lane & 31;
    const int hi   = lane >> 5;

    const int b    = blockIdx.x;
    const int xcd  = b & 7;
    const int slot = b >> 3;
    const int g    = slot & 7;
    const int sub  = slot >> 3;
    const int base  = xcd * ROWS_PER_XCD;
    const int limit = base + ROWS_PER_XCD;

    {
        const uint4* ws = reinterpret_cast<const uint4*>(Wswz) + (size_t)g * 6144;
        uint4* wd = reinterpret_cast<uint4*>(Wlds);
        #pragma unroll
        for (int i = 0; i < 12; ++i) wd[i * 512 + tid] = ws[i * 512 + tid];
    }
    __syncthreads();

    const short8* wbase = reinterpret_cast<const short8*>(Wlds);
    const int jj = g * 32 + l32;
    const float bir = bih[jj], biz = bih[256 + jj], bin_ = bih[512 + jj];
    const float bhr = bhh[jj], bhz = bhh[256 + jj], bhn  = bhh[512 + jj];

    float colmax = -__builtin_inff();

    for (int t = sub; t < NTILES; t += 4) {
        const int wrow0 = base + t * 256 + wave * 32;
        if (wrow0 >= limit) continue;
        const int arow = min(wrow0 + l32, limit - 1);
        const float4* X4 = reinterpret_cast<const float4*>(X) + (size_t)arow * 64;
        const float4* H4 = reinterpret_cast<const float4*>(H) + (size_t)arow * 64;

        float16v acc[6];
        #pragma unroll
        for (int s = 0; s < 6; ++s)
            #pragma unroll
            for (int qq = 0; qq < 16; ++qq) acc[s][qq] = 0.0f;

        float4 xb[2][4], hb[2][4];
        #pragma unroll
        for (int c = 0; c < 2; ++c)
            #pragma unroll
            for (int f = 0; f < 2; ++f) {
                int fi = c * 4 + hi * 2 + f;
                xb[0][c * 2 + f] = X4[fi];
                hb[0][c * 2 + f] = H4[fi];
            }

        #pragma unroll
        for (int qq = 0; qq < 8; ++qq) {
            const int cur = qq & 1, nxt = cur ^ 1;
            if (qq < 7) {
                #pragma unroll
                for (int c = 0; c < 2; ++c)
                    #pragma unroll
                    for (int f = 0; f < 2; ++f) {
                        int fi = (qq * 2 + 2 + c) * 4 + hi * 2 + f;
                        xb[nxt][c * 2 + f] = X4[fi];
                        hb[nxt][c * 2 + f] = H4[fi];
                    }
            }
            short8 ax[2], ah[2];
            #pragma unroll
            for (int c = 0; c < 2; ++c) {
                ax[c] = pack_bf16x8(xb[cur][c * 2], xb[cur][c * 2 + 1]);
                ah[c] = pack_bf16x8(hb[cur][c * 2], hb[cur][c * 2 + 1]);
            }
            #pragma unroll
            for (int c = 0; c < 2; ++c) {
                const int kc = qq * 2 + c;
                const short8* wk = wbase + (kc * 6) * 64 + lane;
                acc[0] = __builtin_amdgcn_mfma_f32_32x32x16_bf16(ax[c], wk[0],   acc[0], 0, 0, 0);
                acc[1] = __builtin_amdgcn_mfma_f32_32x32x16_bf16(ax[c], wk[64],  acc[1], 0, 0, 0);
                acc[2] = __builtin_amdgcn_mfma_f32_32x32x16_bf16(ax[c], wk[128], acc[2], 0, 0, 0);
                acc[3] = __builtin_amdgcn_mfma_f32_32x32x16_bf16(ah[c], wk[192], acc[3], 0, 0, 0);
                acc[4] = __builtin_amdgcn_mfma_f32_32x32x16_bf16(ah[c], wk[256], acc[4], 0, 0, 0);
                acc[5] = __builtin_amdgcn_mfma_f32_32x32x16_bf16(ah[c], wk[320], acc[5], 0, 0, 0);
            }
        }

        #pragma unroll
        for (int reg = 0; reg < 16; ++reg) {
            int rl = (reg & 3) + 8 * (reg >> 2) + 4 * hi;
            int m  = wrow0 + rl;
            if (m < limit) {
                float gir = acc[0][reg] + bir;
                float giz = acc[1][reg] + biz;
                float gin = acc[2][reg] + bin_;
                float ghr = acc[3][reg] + bhr;
                float ghz = acc[4][reg] + bhz;
                float ghn = acc[5][reg] + bhn;
                float r = sigmoid_fast(gir + ghr);
                float z = sigmoid_fast(giz + ghz);
                float n = tanh_fast(gin + r * ghn);
                float hpv = H[(size_t)m * 256 + jj];
                float hv = (1.0f - z) * n + z * hpv;
                int mkk = maskbuf[m];
                __builtin_nontemporal_store(mkk ? hv : 0.0f, &hnew[(size_t)m * 256 + jj]);
                if (mkk) colmax = fmaxf(colmax, hv);
            }
        }
    }

    colmax = fmaxf(colmax, __shfl_xor(colmax, 32));
    if (hi == 0) {
        unsigned bb2 = __builtin_bit_cast(unsigned, colmax);
        unsigned u  = (bb2 & 0x80000000u) ? ~bb2 : (bb2 | 0x80000000u);
        atomicMax(&maxacc[jj], u);
    }
}

__global__ void finalize_kernel(const unsigned int* __restrict__ maxacc,
                                const float* __restrict__ interval,
                                const float* __restrict__ time_w,
                                const float* __restrict__ time_b,
                                float* __restrict__ out)
{
    int j = threadIdx.x;
    unsigned u = maxacc[j];
    unsigned b = (u & 0x80000000u) ? (u & 0x7FFFFFFFu) : ~u;
    float mx = __builtin_bit_cast(float, b);
    float inv = 1.0f / logf(interval[0] + 2.718281828459045f);
    out[j] = mx + tanhf(inv * time_w[j] + time_b[j]);
}

extern "C" void kernel_launch(void* const* d_in, const int* in_sizes, int n_in,
                              void* d_out, int out_size, void* d_ws, size_t ws_size,
                              hipStream_t stream) {
    const float* interval = (const float*)d_in[0];
    const float* co       = (const float*)d_in[2];
    const int*   divided  = (const int*)d_in[3];
    const float* hidden   = (const float*)d_in[7];
    const float* wih      = (const float*)d_in[8];
    const float* whh      = (const float*)d_in[9];
    const float* bih      = (const float*)d_in[10];
    const float* bhh      = (const float*)d_in[11];
    const float* time_w   = (const float*)d_in[12];
    const float* time_b   = (const float*)d_in[13];

    float* out  = (float*)d_out;     // [256] output, then [100000*256] h_new
    float* hnew = out + 256;

    // ws layout:
    //   0        : swizzled bf16 weights (786432 B)
    //   786432   : maxacc (1024 B)
    //   787456   : mask (400000 B)
    //   1187456  : donecnt (64 B)
    //   2097152  : packed bf16 A  X|H fragment chunks (102,400,000 B)
    unsigned short* wswz    = (unsigned short*)d_ws;
    unsigned int*   maxacc  = (unsigned int*)((char*)d_ws + 786432);
    int*            maskbuf = (int*)((char*)d_ws + 787456);
    unsigned int*   donecnt = (unsigned int*)((char*)d_ws + 1187456);
    unsigned short* apack   = (unsigned short*)((char*)d_ws + 2097152);

    const size_t NEED = 2097152ull + 102400000ull;
    const bool packed = (ws_size >= NEED);
    const int pb = packed ? 3125 : 0;        // LDS-transpose pack blocks (32 rows each)

    prep_kernel<<<pb + 584, 256, 0, stream>>>(co, hidden, wih, whh, divided,
                                              wswz, apack, maxacc, maskbuf,
                                              donecnt, pb, packed ? 1 : 0);

    if (packed) {
        gru_main16<<<768, 256, 0, stream>>>(apack, hidden, wswz, bih, bhh,
                                            maskbuf, interval, time_w, time_b,
                                            hnew, maxacc, donecnt, out);
    } else {
        gru_main_legacy<<<256, 512, 0, stream>>>(co, hidden, wswz,
                                                 bih, bhh, maskbuf, hnew, maxacc);
        finalize_kernel<<<1, 256, 0, stream>>>(maxacc, interval, time_w, time_b, out);
    }
}

// Round 5
// 573.899 us; speedup vs baseline: 1.3359x; 1.3359x over previous
//
#include <hip/hip_runtime.h>
#include <hip/hip_bf16.h>
#include <math.h>

#define M_ROWS 100000
#define NG16 6250             // 100000 / 16 groups of 16 rows
#define ROWS_PER_XCD 12500    // legacy path
#define NTILES 49             // legacy path
#define NCHUNK 49152          // weight chunks (16B) total = 768 KB

typedef __attribute__((ext_vector_type(8)))  short  short8;
typedef __attribute__((ext_vector_type(4)))  float  float4v;
typedef __attribute__((ext_vector_type(16))) float  float16v;

__device__ __forceinline__ unsigned short bf16_rne(float f) {
    unsigned u = __builtin_bit_cast(unsigned, f);
    u += 0x7FFFu + ((u >> 16) & 1u);
    return (unsigned short)(u >> 16);
}

__device__ __forceinline__ float sigmoid_fast(float x) {
    return 1.0f / (1.0f + __expf(-x));
}
__device__ __forceinline__ float tanh_fast(float x) {
    return 1.0f - 2.0f / (__expf(2.0f * x) + 1.0f);   // correct limits at +/-inf
}

__device__ __forceinline__ unsigned pack2_rn(float lo, float hi) {
    __hip_bfloat162 t = __float22bfloat162_rn(float2{lo, hi});
    unsigned u;
    __builtin_memcpy(&u, &t, 4);
    return u;
}

__device__ __forceinline__ short8 pack_bf16x8(float4 a, float4 b) {
    union { short8 s; unsigned u[4]; } r;
    r.u[0] = pack2_rn(a.x, a.y);
    r.u[1] = pack2_rn(a.z, a.w);
    r.u[2] = pack2_rn(b.x, b.y);
    r.u[3] = pack2_rn(b.z, b.w);
    return r.s;
}

// ---------------------------------------------------------------------------
// prep (fused) — unchanged from R4 (verified passing):
//  blocks [0, pack_blocks): LDS-staged transpose pack of X,H -> bf16
//    A-fragment chunks, coalesced both sides.
//      chunk index = gq*1024 + kc*128 + mat*64 + lane  (16 B units)
//      lane l holds 8 bf16: row = gq*16+(l&15), k = kc*32+(l>>4)*8+j.
//  next 192 blocks: weight swizzle f32 -> bf16 B-fragment chunks (w16 layout):
//      chunk = ((g16*8+kc)*6+s)*64+lane,
//      outcol = g16*16+(l&15), k = kc*32+(l>>4)*8+j, W-row = (s%3)*256+outcol.
//  next 391 blocks: row mask. last block: max-acc init + done counter.
// ---------------------------------------------------------------------------
__global__ void prep_kernel(const float* __restrict__ X,
                            const float* __restrict__ H,
                            const float* __restrict__ wih,
                            const float* __restrict__ whh,
                            const int* __restrict__ divided,
                            unsigned short* __restrict__ wswz,
                            unsigned short* __restrict__ apack,
                            unsigned int* __restrict__ maxacc,
                            int* __restrict__ maskbuf,
                            unsigned int* __restrict__ donecnt,
                            int pack_blocks, int w16)
{
    __shared__ unsigned short slds[2][32][264];   // 33.8 KB, rows 16B-aligned

    const int b   = blockIdx.x;
    const int tid = threadIdx.x;

    if (b < pack_blocks) {
        const int r0 = b * 32;
        #pragma unroll
        for (int it = 0; it < 16; ++it) {
            const int mat = it >> 3;
            const int idx = (it & 7) * 256 + tid;     // 0..2047
            const int row = idx >> 6;                 // 0..31
            const int c4  = idx & 63;                 // float4 col
            const float* sp = (mat ? H : X) + (size_t)(r0 + row) * 256 + c4 * 4;
            float4 v = *reinterpret_cast<const float4*>(sp);
            uint2 w;
            w.x = pack2_rn(v.x, v.y);
            w.y = pack2_rn(v.z, v.w);
            *reinterpret_cast<uint2*>(&slds[mat][row][c4 * 4]) = w;
        }
        __syncthreads();
        #pragma unroll
        for (int it = 0; it < 8; ++it) {
            const int o    = it * 256 + tid;          // 0..2047
            const int gl   = o >> 10;
            const int kc   = (o >> 7) & 7;
            const int mat  = (o >> 6) & 1;
            const int lane = o & 63;
            const int rl   = gl * 16 + (lane & 15);
            const int col  = kc * 32 + (lane >> 4) * 8;
            short8 v = *reinterpret_cast<const short8*>(&slds[mat][rl][col]);
            reinterpret_cast<short8*>(apack)[(size_t)b * 2048 + o] = v;
        }
        return;
    }

    int bb = b - pack_blocks;
    if (bb < 192) {
        int idx  = bb * 256 + tid;        // < 49152
        int lane = idx & 63;
        int t    = idx >> 6;              // 0..767
        int s    = t % 6;
        int t2   = t / 6;                 // 0..127
        int row, col;
        if (w16) {
            int kc  = t2 & 7;
            int g16 = t2 >> 3;            // 0..15
            row = (s % 3) * 256 + g16 * 16 + (lane & 15);
            col = kc * 32 + (lane >> 4) * 8;
        } else {
            int kc = t2 & 15;
            int g  = t2 >> 4;             // 0..7
            row = (s % 3) * 256 + g * 32 + (lane & 31);
            col = kc * 16 + (lane >> 5) * 8;
        }
        const float* src = (s < 3 ? wih : whh) + (size_t)row * 256 + col;
        float4 a = reinterpret_cast<const float4*>(src)[0];
        float4 c = reinterpret_cast<const float4*>(src)[1];
        uint4 p;
        p.x = (unsigned)bf16_rne(a.x) | ((unsigned)bf16_rne(a.y) << 16);
        p.y = (unsigned)bf16_rne(a.z) | ((unsigned)bf16_rne(a.w) << 16);
        p.z = (unsigned)bf16_rne(c.x) | ((unsigned)bf16_rne(c.y) << 16);
        p.w = (unsigned)bf16_rne(c.z) | ((unsigned)bf16_rne(c.w) << 16);
        reinterpret_cast<uint4*>(wswz)[idx] = p;
    } else if (bb < 192 + 391) {
        int m = (bb - 192) * 256 + tid;
        if (m < M_ROWS)
            maskbuf[m] = (divided[3 * m] > 0) | (divided[3 * m + 1] > 0) | (divided[3 * m + 2] > 0);
    } else {
        maxacc[tid] = 0u;                 // below ordered-map(-inf)
        if (tid == 0) *donecnt = 0u;
    }
}

// ---------------------------------------------------------------------------
// main (16x16x32, M_rep=2, R1 stream structure): 512-thread blocks (8 waves),
// 96 KB LDS = one 32-col weight slice (two contiguous 48 KB g16 halves).
// grid = 256 = (xcd: b&7) x (g32: slot&7) x (sub: slot>>3) — IDENTICAL
// sharing multiplicity to R1 (8 blocks per A-stream, proven FETCH ~103 MB).
// Wave = (rowslot rs 0..3) x (colhalf ch 0..1): owns 2 consecutive 16-row
// groups x 16 cols. Each B-chunk ds_read feeds 2 MFMAs (M_rep=2 halves LDS
// traffic vs R4). acc = 12 x float4 = 48 AGPR; ring 64 VGPR -> big headroom
// for the compiler to pipeline (R1's 184-reg squeeze is gone).
// A-ring: 4-deep, refills at kc>=4 fetch the NEXT pair's kc 0..3 -> no cold
// restart at pair boundaries. Finalize fused into last block to finish.
// ---------------------------------------------------------------------------
__global__ __launch_bounds__(512, 2) void gru_main16x2(
    const unsigned short* __restrict__ Apack,
    const float* __restrict__ H,
    const unsigned short* __restrict__ Wswz,
    const float* __restrict__ bih,
    const float* __restrict__ bhh,
    const int* __restrict__ maskbuf,
    const float* __restrict__ interval,
    const float* __restrict__ time_w,
    const float* __restrict__ time_b,
    float* __restrict__ hnew,
    unsigned int* __restrict__ maxacc,
    unsigned int* __restrict__ donecnt,
    float* __restrict__ out)
{
    __shared__ unsigned short Wlds[49152];        // 96 KB (one g32-slice)
    __shared__ int islast;

    const int tid  = threadIdx.x;
    const int lane = tid & 63;
    const int wave = tid >> 6;                    // 0..7
    const int l16  = lane & 15;
    const int q    = lane >> 4;                   // 0..3
    const int ch   = wave & 1;                    // colhalf
    const int rs   = wave >> 1;                   // rowslot 0..3

    const int b    = blockIdx.x;
    const int xcd  = b & 7;
    const int slot = b >> 3;                      // 0..31
    const int g32  = slot & 7;
    const int sub  = slot >> 3;                   // 0..3

    const int gbeg = xcd * 781 + (xcd < 2 ? xcd : 2);
    const int gend = gbeg + 781 + (xcd < 2 ? 1 : 0);

    // ---- one-time weight stage: contiguous 96 KB slice (g16 pair) -> LDS ----
    {
        const uint4* ws = reinterpret_cast<const uint4*>(Wswz) + (size_t)g32 * 6144;
        uint4* wd = reinterpret_cast<uint4*>(Wlds);
        #pragma unroll
        for (int i = 0; i < 12; ++i) wd[i * 512 + tid] = ws[i * 512 + tid];
    }
    __syncthreads();

    const short8* wbase = reinterpret_cast<const short8*>(Wlds) + ch * 3072;
    const short8* A8b   = reinterpret_cast<const short8*>(Apack);
    const int jj = g32 * 32 + ch * 16 + l16;
    const float bir = bih[jj], biz = bih[256 + jj], bin_ = bih[512 + jj];
    const float bhr = bhh[jj], bhz = bhh[256 + jj], bhn  = bhh[512 + jj];

    float colmax = -__builtin_inff();

    const int first = (sub * 4 + rs) * 2;         // stream offset, step 32
    int gr0 = gbeg + first;                       // always < gend (first<=30)

    // ---- persistent 4-deep A ring: 2 groups x {X,H} ----
    short8 bx0[4], bh0[4], bx1[4], bh1[4];
    {
        const int g1c = (gr0 + 1 < gend) ? gr0 + 1 : gr0;
        const short8* P0 = A8b + (size_t)gr0 * 1024 + lane;
        const short8* P1 = A8b + (size_t)g1c * 1024 + lane;
        #pragma unroll
        for (int p = 0; p < 4; ++p) {
            bx0[p] = P0[p * 128]; bh0[p] = P0[p * 128 + 64];
            bx1[p] = P1[p * 128]; bh1[p] = P1[p * 128 + 64];
        }
    }

    for (; gr0 < gend; gr0 += 32) {
        const int gr1 = gr0 + 1;
        const bool v1 = (gr1 < gend);
        const int g1c = v1 ? gr1 : gr0;

        const short8* A0 = A8b + (size_t)gr0 * 1024 + lane;
        const short8* A1 = A8b + (size_t)g1c * 1024 + lane;

        int n0 = gr0 + 32; if (n0 >= gend) n0 = gr0;         // last-iter clamp
        int n1 = n0 + 1;   if (n1 >= gend) n1 = n0;
        const short8* A0n = A8b + (size_t)n0 * 1024 + lane;
        const short8* A1n = A8b + (size_t)n1 * 1024 + lane;

        // epilogue operand prefetch (completes under MFMAs)
        float hp0[4], hp1[4]; int mk0[4], mk1[4];
        #pragma unroll
        for (int r = 0; r < 4; ++r) {
            const int m0 = gr0 * 16 + q * 4 + r;
            const int m1 = g1c * 16 + q * 4 + r;
            hp0[r] = H[(size_t)m0 * 256 + jj];  mk0[r] = maskbuf[m0];
            hp1[r] = H[(size_t)m1 * 256 + jj];  mk1[r] = maskbuf[m1];
        }

        float4v acc[12];
        #pragma unroll
        for (int s = 0; s < 12; ++s)
            #pragma unroll
            for (int r = 0; r < 4; ++r) acc[s][r] = 0.0f;

        #pragma unroll
        for (int kc = 0; kc < 8; ++kc) {
            const int sl = kc & 3;
            const short8 ax0 = bx0[sl], ah0 = bh0[sl];
            const short8 ax1 = bx1[sl], ah1 = bh1[sl];

            // refill slot 4 ahead; kc>=4 crosses into the next pair
            {
                const short8* P0 = (kc < 4) ? A0 : A0n;
                const short8* P1 = (kc < 4) ? A1 : A1n;
                const int ko = (kc < 4) ? (kc + 4) : (kc - 4);
                bx0[sl] = P0[ko * 128]; bh0[sl] = P0[ko * 128 + 64];
                bx1[sl] = P1[ko * 128]; bh1[sl] = P1[ko * 128 + 64];
            }

            const short8* wk = wbase + kc * 384 + lane;
            const short8 w0 = wk[0],  w1 = wk[64],  w2 = wk[128];
            const short8 w3 = wk[192], w4 = wk[256], w5 = wk[320];
            acc[0]  = __builtin_amdgcn_mfma_f32_16x16x32_bf16(ax0, w0, acc[0],  0, 0, 0);
            acc[6]  = __builtin_amdgcn_mfma_f32_16x16x32_bf16(ax1, w0, acc[6],  0, 0, 0);
            acc[1]  = __builtin_amdgcn_mfma_f32_16x16x32_bf16(ax0, w1, acc[1],  0, 0, 0);
            acc[7]  = __builtin_amdgcn_mfma_f32_16x16x32_bf16(ax1, w1, acc[7],  0, 0, 0);
            acc[2]  = __builtin_amdgcn_mfma_f32_16x16x32_bf16(ax0, w2, acc[2],  0, 0, 0);
            acc[8]  = __builtin_amdgcn_mfma_f32_16x16x32_bf16(ax1, w2, acc[8],  0, 0, 0);
            acc[3]  = __builtin_amdgcn_mfma_f32_16x16x32_bf16(ah0, w3, acc[3],  0, 0, 0);
            acc[9]  = __builtin_amdgcn_mfma_f32_16x16x32_bf16(ah1, w3, acc[9],  0, 0, 0);
            acc[4]  = __builtin_amdgcn_mfma_f32_16x16x32_bf16(ah0, w4, acc[4],  0, 0, 0);
            acc[10] = __builtin_amdgcn_mfma_f32_16x16x32_bf16(ah1, w4, acc[10], 0, 0, 0);
            acc[5]  = __builtin_amdgcn_mfma_f32_16x16x32_bf16(ah0, w5, acc[5],  0, 0, 0);
            acc[11] = __builtin_amdgcn_mfma_f32_16x16x32_bf16(ah1, w5, acc[11], 0, 0, 0);
        }

        // ---- fused GRU epilogue: C/D col = lane&15 (=jj), row = q*4 + r ----
        #pragma unroll
        for (int r = 0; r < 4; ++r) {
            const int m = gr0 * 16 + q * 4 + r;
            float gir = acc[0][r] + bir;
            float giz = acc[1][r] + biz;
            float gin = acc[2][r] + bin_;
            float ghr = acc[3][r] + bhr;
            float ghz = acc[4][r] + bhz;
            float ghn = acc[5][r] + bhn;
            float rr = sigmoid_fast(gir + ghr);
            float z  = sigmoid_fast(giz + ghz);
            float n  = tanh_fast(gin + rr * ghn);
            float hv = (1.0f - z) * n + z * hp0[r];
            __builtin_nontemporal_store(mk0[r] ? hv : 0.0f, &hnew[(size_t)m * 256 + jj]);
            if (mk0[r]) colmax = fmaxf(colmax, hv);
        }
        if (v1) {
            #pragma unroll
            for (int r = 0; r < 4; ++r) {
                const int m = gr1 * 16 + q * 4 + r;
                float gir = acc[6][r]  + bir;
                float giz = acc[7][r]  + biz;
                float gin = acc[8][r]  + bin_;
                float ghr = acc[9][r]  + bhr;
                float ghz = acc[10][r] + bhz;
                float ghn = acc[11][r] + bhn;
                float rr = sigmoid_fast(gir + ghr);
                float z  = sigmoid_fast(giz + ghz);
                float n  = tanh_fast(gin + rr * ghn);
                float hv = (1.0f - z) * n + z * hp1[r];
                __builtin_nontemporal_store(mk1[r] ? hv : 0.0f, &hnew[(size_t)m * 256 + jj]);
                if (mk1[r]) colmax = fmaxf(colmax, hv);
            }
        }
    }

    // lanes sharing a column jj within a wave: lane, lane^16, lane^32, lane^48
    colmax = fmaxf(colmax, __shfl_xor(colmax, 16));
    colmax = fmaxf(colmax, __shfl_xor(colmax, 32));
    if (lane < 16) {
        unsigned bb2 = __builtin_bit_cast(unsigned, colmax);
        unsigned u   = (bb2 & 0x80000000u) ? ~bb2 : (bb2 | 0x80000000u);
        atomicMax(&maxacc[jj], u);
    }

    // ---- fused finalize: last block to finish ----
    __syncthreads();
    if (tid == 0) {
        __threadfence();
        islast = (atomicAdd(donecnt, 1u) == 255u) ? 1 : 0;
    }
    __syncthreads();
    if (islast && tid < 256) {
        unsigned u   = ((volatile unsigned int*)maxacc)[tid];
        unsigned bb2 = (u & 0x80000000u) ? (u & 0x7FFFFFFFu) : ~u;
        float mx  = __builtin_bit_cast(float, bb2);
        float inv = 1.0f / logf(interval[0] + 2.718281828459045f);
        out[tid]  = mx + tanhf(inv * time_w[tid] + time_b[tid]);
    }
}

// ---------------------------------------------------------------------------
// legacy path (fallback when workspace is too small for the packed-A buffer)
// ---------------------------------------------------------------------------
__global__ __launch_bounds__(512, 2) void gru_main_legacy(
    const float* __restrict__ X,
    const float* __restrict__ H,
    const unsigned short* __restrict__ Wswz,
    const float* __restrict__ bih,
    const float* __restrict__ bhh,
    const int* __restrict__ maskbuf,
    float* __restrict__ hnew,
    unsigned int* __restrict__ maxacc)
{
    __shared__ unsigned short Wlds[NCHUNK];

    const int tid  = threadIdx.x;
    const int lane = tid & 63;
    const int wave = tid >> 6;
    const int l32  = lane & 31;
    const int hi   = lane >> 5;

    const int b    = blockIdx.x;
    const int xcd  = b & 7;
    const int slot = b >> 3;
    const int g    = slot & 7;
    const int sub  = slot >> 3;
    const int base  = xcd * ROWS_PER_XCD;
    const int limit = base + ROWS_PER_XCD;

    {
        const uint4* ws = reinterpret_cast<const uint4*>(Wswz) + (size_t)g * 6144;
        uint4* wd = reinterpret_cast<uint4*>(Wlds);
        #pragma unroll
        for (int i = 0; i < 12; ++i) wd[i * 512 + tid] = ws[i * 512 + tid];
    }
    __syncthreads();

    const short8* wbase = reinterpret_cast<const short8*>(Wlds);
    const int jj = g * 32 + l32;
    const float bir = bih[jj], biz = bih[256 + jj], bin_ = bih[512 + jj];
    const float bhr = bhh[jj], bhz = bhh[256 + jj], bhn  = bhh[512 + jj];

    float colmax = -__builtin_inff();

    for (int t = sub; t < NTILES; t += 4) {
        const int wrow0 = base + t * 256 + wave * 32;
        if (wrow0 >= limit) continue;
        const int arow = min(wrow0 + l32, limit - 1);
        const float4* X4 = reinterpret_cast<const float4*>(X) + (size_t)arow * 64;
        const float4* H4 = reinterpret_cast<const float4*>(H) + (size_t)arow * 64;

        float16v acc[6];
        #pragma unroll
        for (int s = 0; s < 6; ++s)
            #pragma unroll
            for (int qq = 0; qq < 16; ++qq) acc[s][qq] = 0.0f;

        float4 xb[2][4], hb[2][4];
        #pragma unroll
        for (int c = 0; c < 2; ++c)
            #pragma unroll
            for (int f = 0; f < 2; ++f) {
                int fi = c * 4 + hi * 2 + f;
                xb[0][c * 2 + f] = X4[fi];
                hb[0][c * 2 + f] = H4[fi];
            }

        #pragma unroll
        for (int qq = 0; qq < 8; ++qq) {
            const int cur = qq & 1, nxt = cur ^ 1;
            if (qq < 7) {
                #pragma unroll
                for (int c = 0; c < 2; ++c)
                    #pragma unroll
                    for (int f = 0; f < 2; ++f) {
                        int fi = (qq * 2 + 2 + c) * 4 + hi * 2 + f;
                        xb[nxt][c * 2 + f] = X4[fi];
                        hb[nxt][c * 2 + f] = H4[fi];
                    }
            }
            short8 ax[2], ah[2];
            #pragma unroll
            for (int c = 0; c < 2; ++c) {
                ax[c] = pack_bf16x8(xb[cur][c * 2], xb[cur][c * 2 + 1]);
                ah[c] = pack_bf16x8(hb[cur][c * 2], hb[cur][c * 2 + 1]);
            }
            #pragma unroll
            for (int c = 0; c < 2; ++c) {
                const int kc = qq * 2 + c;
                const short8* wk = wbase + (kc * 6) * 64 + lane;
                acc[0] = __builtin_amdgcn_mfma_f32_32x32x16_bf16(ax[c], wk[0],   acc[0], 0, 0, 0);
                acc[1] = __builtin_amdgcn_mfma_f32_32x32x16_bf16(ax[c], wk[64],  acc[1], 0, 0, 0);
                acc[2] = __builtin_amdgcn_mfma_f32_32x32x16_bf16(ax[c], wk[128], acc[2], 0, 0, 0);
                acc[3] = __builtin_amdgcn_mfma_f32_32x32x16_bf16(ah[c], wk[192], acc[3], 0, 0, 0);
                acc[4] = __builtin_amdgcn_mfma_f32_32x32x16_bf16(ah[c], wk[256], acc[4], 0, 0, 0);
                acc[5] = __builtin_amdgcn_mfma_f32_32x32x16_bf16(ah[c], wk[320], acc[5], 0, 0, 0);
            }
        }

        #pragma unroll
        for (int reg = 0; reg < 16; ++reg) {
            int rl = (reg & 3) + 8 * (reg >> 2) + 4 * hi;
            int m  = wrow0 + rl;
            if (m < limit) {
                float gir = acc[0][reg] + bir;
                float giz = acc[1][reg] + biz;
                float gin = acc[2][reg] + bin_;
                float ghr = acc[3][reg] + bhr;
                float ghz = acc[4][reg] + bhz;
                float ghn = acc[5][reg] + bhn;
                float r = sigmoid_fast(gir + ghr);
                float z = sigmoid_fast(giz + ghz);
                float n = tanh_fast(gin + r * ghn);
                float hpv = H[(size_t)m * 256 + jj];
                float hv = (1.0f - z) * n + z * hpv;
                int mkk = maskbuf[m];
                __builtin_nontemporal_store(mkk ? hv : 0.0f, &hnew[(size_t)m * 256 + jj]);
                if (mkk) colmax = fmaxf(colmax, hv);
            }
        }
    }

    colmax = fmaxf(colmax, __shfl_xor(colmax, 32));
    if (hi == 0) {
        unsigned bb2 = __builtin_bit_cast(unsigned, colmax);
        unsigned u  = (bb2 & 0x80000000u) ? ~bb2 : (bb2 | 0x80000000u);
        atomicMax(&maxacc[jj], u);
    }
}

__global__ void finalize_kernel(const unsigned int* __restrict__ maxacc,
                                const float* __restrict__ interval,
                                const float* __restrict__ time_w,
                                const float* __restrict__ time_b,
                                float* __restrict__ out)
{
    int j = threadIdx.x;
    unsigned u = maxacc[j];
    unsigned b = (u & 0x80000000u) ? (u & 0x7FFFFFFFu) : ~u;
    float mx = __builtin_bit_cast(float, b);
    float inv = 1.0f / logf(interval[0] + 2.718281828459045f);
    out[j] = mx + tanhf(inv * time_w[j] + time_b[j]);
}

extern "C" void kernel_launch(void* const* d_in, const int* in_sizes, int n_in,
                              void* d_out, int out_size, void* d_ws, size_t ws_size,
                              hipStream_t stream) {
    const float* interval = (const float*)d_in[0];
    const float* co       = (const float*)d_in[2];
    const int*   divided  = (const int*)d_in[3];
    const float* hidden   = (const float*)d_in[7];
    const float* wih      = (const float*)d_in[8];
    const float* whh      = (const float*)d_in[9];
    const float* bih      = (const float*)d_in[10];
    const float* bhh      = (const float*)d_in[11];
    const float* time_w   = (const float*)d_in[12];
    const float* time_b   = (const float*)d_in[13];

    float* out  = (float*)d_out;     // [256] output, then [100000*256] h_new
    float* hnew = out + 256;

    // ws layout:
    //   0        : swizzled bf16 weights (786432 B)
    //   786432   : maxacc (1024 B)
    //   787456   : mask (400000 B)
    //   1187456  : donecnt (64 B)
    //   2097152  : packed bf16 A  X|H fragment chunks (102,400,000 B)
    unsigned short* wswz    = (unsigned short*)d_ws;
    unsigned int*   maxacc  = (unsigned int*)((char*)d_ws + 786432);
    int*            maskbuf = (int*)((char*)d_ws + 787456);
    unsigned int*   donecnt = (unsigned int*)((char*)d_ws + 1187456);
    unsigned short* apack   = (unsigned short*)((char*)d_ws + 2097152);

    const size_t NEED = 2097152ull + 102400000ull;
    const bool packed = (ws_size >= NEED);
    const int pb = packed ? 3125 : 0;        // LDS-transpose pack blocks (32 rows each)

    prep_kernel<<<pb + 584, 256, 0, stream>>>(co, hidden, wih, whh, divided,
                                              wswz, apack, maxacc, maskbuf,
                                              donecnt, pb, packed ? 1 : 0);

    if (packed) {
        gru_main16x2<<<256, 512, 0, stream>>>(apack, hidden, wswz, bih, bhh,
                                              maskbuf, interval, time_w, time_b,
                                              hnew, maxacc, donecnt, out);
    } else {
        gru_main_legacy<<<256, 512, 0, stream>>>(co, hidden, wswz,
                                                 bih, bhh, maskbuf, hnew, maxacc);
        finalize_kernel<<<1, 256, 0, stream>>>(maxacc, interval, time_w, time_b, out);
    }
}